// Round 4
// baseline (6900.717 us; speedup 1.0000x reference)
//
#include <hip/hip_runtime.h>
#include <stdint.h>

typedef _Float16 half8 __attribute__((ext_vector_type(8)));  // 8 fp16 (4 VGPR) MFMA frag
typedef __attribute__((ext_vector_type(4))) float f4;        // fp32x4 accum
typedef __attribute__((ext_vector_type(4))) unsigned int u32x4;
typedef __attribute__((ext_vector_type(2))) unsigned int u32x2;

#define LDA  296   // halves per LDS A row (288 data + 8 pad; 148 words ≡ 4 mod 8 -> 2-way only)
#define EXS  34    // exchange stride (floats)
#define HSTR 56    // sH stride (halves), 112B: 16B-aligned, 28 words ≡ 4 mod 8 -> 2-way only

__device__ __forceinline__ float sigm(float x) { return 1.0f / (1.0f + __expf(-x)); }
__device__ __forceinline__ float tanh_(float x) { return 1.0f - 2.0f / (__expf(2.0f * x) + 1.0f); } // overflow-safe

// ---------------- prologue kernels (unchanged from R2) ----------------

extern "C" __global__ void __launch_bounds__(256) k_wcat(
    const float* __restrict__ Wih, const float* __restrict__ Whh,
    _Float16* __restrict__ WA, _Float16* __restrict__ WB)
{
    int idx = blockIdx.x * 256 + threadIdx.x;        // grid 4608 -> exactly 2048*576
    int n = idx / 576, k = idx % 576;
    float v = (k < 64) ? Wih[n * 64 + k] : Whh[n * 512 + (k - 64)];
    _Float16 b = (_Float16)v;
    WA[idx] = b;
    if (k < 64) WB[idx] = b;
}

extern "C" __global__ void __launch_bounds__(256) k_comb(
    const float* __restrict__ Wih, const float* __restrict__ Whh,
    const float* __restrict__ Wo, _Float16* __restrict__ WB)
{
    int bx = blockIdx.x;                             // grid 4096
    int n = bx >> 1;
    int kh = ((bx & 1) << 8) + threadIdx.x;          // 0..511
    float acc = Whh[n * 512 + kh];
    #pragma unroll 16
    for (int p = 0; p < 64; ++p)
        acc += Wih[n * 64 + p] * Wo[p * 512 + kh];
    WB[n * 576 + 64 + kh] = (_Float16)acc;
}

extern "C" __global__ void __launch_bounds__(256) k_misc(
    const float* __restrict__ Wo, const float* __restrict__ bih, const float* __restrict__ bhh,
    const float* __restrict__ Wih, const float* __restrict__ bo, const float* __restrict__ x,
    _Float16* __restrict__ WoB, float* __restrict__ b0v, float* __restrict__ b1v,
    float* __restrict__ yf0, float* __restrict__ yf1,
    _Float16* __restrict__ yh0, _Float16* __restrict__ yh1,
    _Float16* __restrict__ yl0, _Float16* __restrict__ yl1)
{
    int idx = blockIdx.x * 256 + threadIdx.x;        // grid 392
    if (idx < 32768) { WoB[idx] = (_Float16)Wo[idx]; return; }
    if (idx < 34816) {
        int n = idx - 32768;
        float b = bih[n] + bhh[n];
        b0v[n] = b;
        float a = b;
        #pragma unroll 16
        for (int p = 0; p < 64; ++p) a += Wih[n * 64 + p] * bo[p];
        b1v[n] = a;
        return;
    }
    if (idx < 100352) {
        int e = idx - 34816;
        int m = e >> 6, nn = e & 63;
        float v = x[m * 2048 + 31 * 64 + nn];        // x[:, -1, :]
        yf0[e] = v; yf1[e] = v;
        _Float16 hi = (_Float16)v;
        _Float16 lo = (_Float16)(v - (float)hi);
        yh0[e] = hi; yh1[e] = hi;
        yl0[e] = lo; yl1[e] = lo;
    }
}

extern "C" __global__ void __launch_bounds__(256) k_h0(
    const float* __restrict__ z, const float* __restrict__ Wp, const float* __restrict__ bp,
    float* __restrict__ cst, _Float16* __restrict__ hh0, _Float16* __restrict__ hl0)
{
    int bx = blockIdx.x;                             // grid 2048
    int m = bx >> 1;
    int n = ((bx & 1) << 8) + threadIdx.x;
    float acc = bp[n];
    const f4* zr = (const f4*)&z[m * 128];
    const f4* wr = (const f4*)&Wp[n * 128];
    #pragma unroll 8
    for (int p = 0; p < 32; ++p) {
        f4 zv = zr[p], wv = wr[p];
        acc += zv[0]*wv[0] + zv[1]*wv[1] + zv[2]*wv[2] + zv[3]*wv[3];
    }
    cst[m * 512 + n] = acc;
    _Float16 hi = (_Float16)acc;
    hh0[m * 512 + n] = hi;
    hl0[m * 512 + n] = (_Float16)(acc - (float)hi);
}

// ---------------- grid barrier (persistent kernel, 256 co-resident blocks) ----------------
__device__ __forceinline__ void grid_bar(unsigned int* cnt, unsigned int target) {
    __syncthreads();                                  // block's stores issued (s_waitcnt at barrier)
    if (threadIdx.x == 0) {
        __hip_atomic_fetch_add(cnt, 1u, __ATOMIC_RELEASE, __HIP_MEMORY_SCOPE_AGENT); // wb before count
        while (__hip_atomic_load(cnt, __ATOMIC_RELAXED, __HIP_MEMORY_SCOPE_AGENT) < target)
            __builtin_amdgcn_s_sleep(2);
    }
    __syncthreads();
    __builtin_amdgcn_fence(__ATOMIC_ACQUIRE, "agent");   // inv L1/L2 before reads
}

// ---------------- persistent step-loop kernel ----------------
// grid 256: block (mt, s): rows m0..m0+64, h-cols j0..j0+32 (all 4 gate quadrants)
// A layout (K=1152): [y_hi(0..64) | y_lo(64..128) | h_hi(128..640) | h_lo(640..1152)]
// One grid barrier per step (y-resolution uses step-(t-1) Delta partials; gates use y_{t-2}).
extern "C" __global__ void __launch_bounds__(256) k_loop(
    const _Float16* __restrict__ WA, const _Float16* __restrict__ WB,
    const float* __restrict__ b0v, const float* __restrict__ b1v,
    const _Float16* __restrict__ WoB, const float* __restrict__ bout,
    _Float16* __restrict__ hh0, _Float16* __restrict__ hh1,
    _Float16* __restrict__ hl0, _Float16* __restrict__ hl1,
    float* __restrict__ cst,
    float* __restrict__ yf0, float* __restrict__ yf1,
    _Float16* __restrict__ yh0, _Float16* __restrict__ yh1,
    _Float16* __restrict__ yl0, _Float16* __restrict__ yl1,
    float* __restrict__ dl0, float* __restrict__ dl1,
    float* __restrict__ out, unsigned int* __restrict__ bar)
{
    __shared__ __align__(16) unsigned char smem[49152];
    _Float16* sA  = (_Float16*)smem;                             // A chunk: 64 x LDA (37,888 B)
    float*    sEx = (float*)smem;                                // overlay: [4][64][EXS] = 34,816 B
    _Float16* sHh = (_Float16*)(smem + 34816);                   // [64][HSTR] = 7,168 B
    _Float16* sHl = (_Float16*)(smem + 34816 + 7168);            // [64][HSTR]

    const int tid = threadIdx.x;
    const int bx  = blockIdx.x;
    const int mt  = bx >> 4, s = bx & 15;
    const int m0  = mt * 64, j0 = s * 32;

    const int wv = tid >> 6, lane = tid & 63, l15 = lane & 15, quad = lane >> 4;
    const int quad8 = quad * 8;
    const int brow0 = (wv * 512 + j0 + l15) * 576;
    const int brow1 = (wv * 512 + j0 + 16 + l15) * 576;
    const half8 bw = *(const half8*)&WoB[(wv * 16 + l15) * 512 + j0 + quad8];   // loop-invariant

    const f4 zero = {0.0f, 0.0f, 0.0f, 0.0f};

    #pragma unroll 1
    for (int t = 0; t <= 128; ++t) {
        const int pi = t & 1;
        const _Float16* Wcat  = t ? WB : WA;
        const float*    bias  = t ? b1v : b0v;
        const _Float16* hh_in = pi ? hh1 : hh0;   _Float16* hh_out = pi ? hh0 : hh1;
        const _Float16* hl_in = pi ? hl1 : hl0;   _Float16* hl_out = pi ? hl0 : hl1;
        const float*    yf_in = pi ? yf1 : yf0;   float*    yf_out = pi ? yf0 : yf1;
        const _Float16* yh_in = pi ? yh1 : yh0;   _Float16* yh_out = pi ? yh0 : yh1;
        const _Float16* yl_in = pi ? yl1 : yl0;   _Float16* yl_out = pi ? yl0 : yl1;
        const float*    dl_in = pi ? dl0 : dl1;   float*    dl_out = pi ? dl1 : dl0;

        // ---- resolve y_{t-1} = y_{t-2} + b_out + sum_s Delta_{t-1,s} (4 rows per block) ----
        if (t >= 1 && tid < 64) {
            int row = m0 + s * 4 + (tid >> 4);
            int c4  = (tid & 15) * 4;
            f4 a = *(const f4*)&yf_in[row * 64 + c4];
            a += *(const f4*)&bout[c4];
            #pragma unroll
            for (int sp = 0; sp < 16; ++sp)
                a += *(const f4*)&dl_in[sp * 65536 + row * 64 + c4];
            *(f4*)&yf_out[row * 64 + c4] = a;
            *(f4*)&out[row * 8192 + (t - 1) * 64 + c4] = a;
            _Float16 hi4[4], lo4[4];
            #pragma unroll
            for (int x = 0; x < 4; ++x) {
                hi4[x] = (_Float16)a[x];
                lo4[x] = (_Float16)(a[x] - (float)hi4[x]);
            }
            *(u32x2*)&yh_out[row * 64 + c4] = *(u32x2*)hi4;
            *(u32x2*)&yl_out[row * 64 + c4] = *(u32x2*)lo4;
        }
        if (t >= 128) break;

        f4 acc[4][2];
        #pragma unroll
        for (int a = 0; a < 4; ++a) { acc[a][0] = zero; acc[a][1] = zero; }

        // ---- 4 staged chunks of K=288 over the split-A (K=1152) gates GEMM ----
        #pragma unroll
        for (int ch = 0; ch < 4; ++ch) {
            if (ch) __syncthreads();                 // previous chunk's MFMAs done
            #pragma unroll
            for (int it = 0; it < 9; ++it) {         // 9*256*16B = 64 rows x 288 halves
                int i4 = it * 256 + tid;
                int r = i4 / 36, cc = (i4 % 36) * 8;
                int g = ch * 288 + cc;
                const _Float16* src;
                if (g < 64)       src = &yh_in[(m0 + r) * 64 + g];
                else if (g < 128) src = &yl_in[(m0 + r) * 64 + (g - 64)];
                else if (g < 640) src = &hh_in[(m0 + r) * 512 + (g - 128)];
                else              src = &hl_in[(m0 + r) * 512 + (g - 640)];
                *(u32x4*)&sA[r * LDA + cc] = *(const u32x4*)src;
            }
            __syncthreads();
            #pragma unroll
            for (int kc = 0; kc < 9; ++kc) {
                const int g0  = ch * 288 + kc * 32;
                const int bc0 = (g0 < 64) ? g0 : ((g0 < 640) ? g0 - 64 : g0 - 576);
                int kq = kc * 32 + quad8;
                int bq = bc0 + quad8;
                half8 a0 = *(const half8*)&sA[(l15     ) * LDA + kq];
                half8 a1 = *(const half8*)&sA[(l15 + 16) * LDA + kq];
                half8 a2 = *(const half8*)&sA[(l15 + 32) * LDA + kq];
                half8 a3 = *(const half8*)&sA[(l15 + 48) * LDA + kq];
                half8 b0 = *(const half8*)&Wcat[brow0 + bq];
                half8 b1 = *(const half8*)&Wcat[brow1 + bq];
                acc[0][0] = __builtin_amdgcn_mfma_f32_16x16x32_f16(a0, b0, acc[0][0], 0, 0, 0);
                acc[1][0] = __builtin_amdgcn_mfma_f32_16x16x32_f16(a1, b0, acc[1][0], 0, 0, 0);
                acc[2][0] = __builtin_amdgcn_mfma_f32_16x16x32_f16(a2, b0, acc[2][0], 0, 0, 0);
                acc[3][0] = __builtin_amdgcn_mfma_f32_16x16x32_f16(a3, b0, acc[3][0], 0, 0, 0);
                acc[0][1] = __builtin_amdgcn_mfma_f32_16x16x32_f16(a0, b1, acc[0][1], 0, 0, 0);
                acc[1][1] = __builtin_amdgcn_mfma_f32_16x16x32_f16(a1, b1, acc[1][1], 0, 0, 0);
                acc[2][1] = __builtin_amdgcn_mfma_f32_16x16x32_f16(a2, b1, acc[2][1], 0, 0, 0);
                acc[3][1] = __builtin_amdgcn_mfma_f32_16x16x32_f16(a3, b1, acc[3][1], 0, 0, 0);
            }
        }
        __syncthreads();                              // sA dead -> overlay exchange

        // ---- gate exchange: wave wv = quadrant wv (i,f,g,o). D: col=lane&15, row=quad*4+reg ----
        #pragma unroll
        for (int a = 0; a < 4; ++a)
            #pragma unroll
            for (int b = 0; b < 2; ++b)
                #pragma unroll
                for (int r = 0; r < 4; ++r)
                    sEx[(wv * 64 + a * 16 + quad * 4 + r) * EXS + b * 16 + l15] = acc[a][b][r];
        __syncthreads();

        // ---- LSTM cell update: thread -> row m, 8 h-cols ----
        {
            int m = tid >> 2, jb = (tid & 3) * 8;
            int jcol = j0 + jb;
            int crow = (m0 + m) * 512 + jcol;
            f4 c0 = *(const f4*)&cst[crow];
            f4 c1 = *(const f4*)&cst[crow + 4];
            _Float16 hi8[8], lo8[8];
            #pragma unroll
            for (int x = 0; x < 8; ++x) {
                float gi = sEx[(0 * 64 + m) * EXS + jb + x] + bias[       jcol + x];
                float gf = sEx[(1 * 64 + m) * EXS + jb + x] + bias[ 512 + jcol + x];
                float gg = sEx[(2 * 64 + m) * EXS + jb + x] + bias[1024 + jcol + x];
                float go = sEx[(3 * 64 + m) * EXS + jb + x] + bias[1536 + jcol + x];
                float iv = sigm(gi), fv = sigm(gf), gv = tanh_(gg), ov = sigm(go);
                float cold = (x < 4) ? c0[x] : c1[x - 4];
                float cn = fv * cold + iv * gv;
                float hn = ov * tanh_(cn);
                if (x < 4) c0[x] = cn; else c1[x - 4] = cn;
                _Float16 hi = (_Float16)hn;
                hi8[x] = hi;
                lo8[x] = (_Float16)(hn - (float)hi);
            }
            *(f4*)&cst[crow]     = c0;
            *(f4*)&cst[crow + 4] = c1;
            *(u32x4*)&hh_out[crow]       = *(u32x4*)hi8;
            *(u32x4*)&hl_out[crow]       = *(u32x4*)lo8;
            *(u32x4*)&sHh[m * HSTR + jb] = *(u32x4*)hi8;
            *(u32x4*)&sHl[m * HSTR + jb] = *(u32x4*)lo8;
        }
        __syncthreads();

        // ---- Delta partial: dl_out[s] = (h_hi+h_lo)(strip) @ Wout^T, K=32 per m-tile ----
        {
            f4 d[4];
            #pragma unroll
            for (int a = 0; a < 4; ++a) d[a] = zero;
            #pragma unroll
            for (int a = 0; a < 4; ++a) {
                half8 ahh = *(const half8*)&sHh[(a * 16 + l15) * HSTR + quad8];
                half8 ahl = *(const half8*)&sHl[(a * 16 + l15) * HSTR + quad8];
                d[a] = __builtin_amdgcn_mfma_f32_16x16x32_f16(ahh, bw, d[a], 0, 0, 0);
                d[a] = __builtin_amdgcn_mfma_f32_16x16x32_f16(ahl, bw, d[a], 0, 0, 0);
            }
            #pragma unroll
            for (int a = 0; a < 4; ++a)
                #pragma unroll
                for (int r = 0; r < 4; ++r)
                    dl_out[s * 65536 + (m0 + a * 16 + quad * 4 + r) * 64 + wv * 16 + l15] = d[a][r];
        }

        grid_bar(bar, 256u * (unsigned)(t + 1));
    }
}

// ---------------- host ----------------
extern "C" void kernel_launch(void* const* d_in, const int* in_sizes, int n_in,
                              void* d_out, int out_size, void* d_ws, size_t ws_size,
                              hipStream_t stream)
{
    const float* z   = (const float*)d_in[0];
    const float* x   = (const float*)d_in[1];
    const float* Wih = (const float*)d_in[2];
    const float* Whh = (const float*)d_in[3];
    const float* bih = (const float*)d_in[4];
    const float* bhh = (const float*)d_in[5];
    const float* Wp  = (const float*)d_in[6];
    const float* bp  = (const float*)d_in[7];
    const float* Wo  = (const float*)d_in[8];
    const float* bo  = (const float*)d_in[9];

    char* w = (char*)d_ws;
    _Float16* WA  = (_Float16*)w; w += 2359296;   // [2048][576] fp16
    _Float16* WB  = (_Float16*)w; w += 2359296;
    _Float16* WoB = (_Float16*)w; w += 65536;     // [64][512] fp16
    float* b0v = (float*)w; w += 8192;
    float* b1v = (float*)w; w += 8192;
    _Float16* hh[2];
    hh[0] = (_Float16*)w; w += 1048576;
    hh[1] = (_Float16*)w; w += 1048576;
    _Float16* hl[2];
    hl[0] = (_Float16*)w; w += 1048576;
    hl[1] = (_Float16*)w; w += 1048576;
    float* cst = (float*)w; w += 2097152;
    float* yf[2];
    yf[0] = (float*)w; w += 262144;
    yf[1] = (float*)w; w += 262144;
    _Float16* yh[2];
    yh[0] = (_Float16*)w; w += 131072;
    yh[1] = (_Float16*)w; w += 131072;
    _Float16* yl[2];
    yl[0] = (_Float16*)w; w += 131072;
    yl[1] = (_Float16*)w; w += 131072;
    float* dl[2];
    dl[0] = (float*)w; w += 4194304;              // [16][1024][64] fp32
    dl[1] = (float*)w; w += 4194304;
    unsigned int* bar = (unsigned int*)w; w += 64;
    float* out = (float*)d_out;

    (void)hipMemsetAsync(bar, 0, 64, stream);
    k_wcat<<<4608, 256, 0, stream>>>(Wih, Whh, WA, WB);
    k_comb<<<4096, 256, 0, stream>>>(Wih, Whh, Wo, WB);
    k_misc<<<392, 256, 0, stream>>>(Wo, bih, bhh, Wih, bo, x, WoB, b0v, b1v,
                                    yf[0], yf[1], yh[0], yh[1], yl[0], yl[1]);
    k_h0<<<2048, 256, 0, stream>>>(z, Wp, bp, cst, hh[0], hl[0]);

    k_loop<<<256, 256, 0, stream>>>(
        WA, WB, b0v, b1v, WoB, bo,
        hh[0], hh[1], hl[0], hl[1], cst,
        yf[0], yf[1], yh[0], yh[1], yl[0], yl[1],
        dl[0], dl[1], out, bar);
}

// Round 6
// 5478.807 us; speedup vs baseline: 1.2595x; 1.2595x over previous
//
#include <hip/hip_runtime.h>
#include <stdint.h>

typedef _Float16 half8 __attribute__((ext_vector_type(8)));  // 8 fp16 (4 VGPR) MFMA frag
typedef __attribute__((ext_vector_type(4))) float f4;        // fp32x4 accum
typedef __attribute__((ext_vector_type(4))) unsigned int u32x4;

#define LDA  296   // halves per LDS A row; word-stride 148 = 4*37 (37 odd -> b128 conflict-free)
#define EXS  33    // exchange stride (floats), odd -> <=2-way banks on cell-update reads
#define HSTR 56    // sH stride (halves); word-stride 28 = 4*7 (7 odd -> conflict-free)

typedef unsigned long long u64;

__device__ __forceinline__ float sigm(float x) { return 1.0f / (1.0f + __expf(-x)); }
__device__ __forceinline__ float tanh_(float x) { return 1.0f - 2.0f / (__expf(2.0f * x) + 1.0f); } // overflow-safe

// agent-scope relaxed 8B atomics: per-access coherent (no blanket L2 invalidate needed)
__device__ __forceinline__ u64 ald(const void* p) {
    return __hip_atomic_load((const u64*)p, __ATOMIC_RELAXED, __HIP_MEMORY_SCOPE_AGENT);
}
__device__ __forceinline__ void ast(void* p, u64 v) {
    __hip_atomic_store((u64*)p, v, __ATOMIC_RELAXED, __HIP_MEMORY_SCOPE_AGENT);
}
__device__ __forceinline__ f4 ald16f(const float* p) {           // 16B coherent load -> f4
    u64 a = ald(p), b = ald(p + 2);
    f4 r;
    r[0] = __uint_as_float((unsigned)a); r[1] = __uint_as_float((unsigned)(a >> 32));
    r[2] = __uint_as_float((unsigned)b); r[3] = __uint_as_float((unsigned)(b >> 32));
    return r;
}

// ---------------- prologue kernels (unchanged) ----------------

extern "C" __global__ void __launch_bounds__(256) k_wcat(
    const float* __restrict__ Wih, const float* __restrict__ Whh,
    _Float16* __restrict__ WA, _Float16* __restrict__ WB)
{
    int idx = blockIdx.x * 256 + threadIdx.x;        // grid 4608 -> exactly 2048*576
    int n = idx / 576, k = idx % 576;
    float v = (k < 64) ? Wih[n * 64 + k] : Whh[n * 512 + (k - 64)];
    _Float16 b = (_Float16)v;
    WA[idx] = b;
    if (k < 64) WB[idx] = b;
}

extern "C" __global__ void __launch_bounds__(256) k_comb(
    const float* __restrict__ Wih, const float* __restrict__ Whh,
    const float* __restrict__ Wo, _Float16* __restrict__ WB)
{
    int bx = blockIdx.x;                             // grid 4096
    int n = bx >> 1;
    int kh = ((bx & 1) << 8) + threadIdx.x;          // 0..511
    float acc = Whh[n * 512 + kh];
    #pragma unroll 16
    for (int p = 0; p < 64; ++p)
        acc += Wih[n * 64 + p] * Wo[p * 512 + kh];
    WB[n * 576 + 64 + kh] = (_Float16)acc;
}

extern "C" __global__ void __launch_bounds__(256) k_misc(
    const float* __restrict__ Wo, const float* __restrict__ bih, const float* __restrict__ bhh,
    const float* __restrict__ Wih, const float* __restrict__ bo, const float* __restrict__ x,
    _Float16* __restrict__ WoB, float* __restrict__ b0v, float* __restrict__ b1v,
    float* __restrict__ yf0, float* __restrict__ yf1,
    _Float16* __restrict__ yh0, _Float16* __restrict__ yh1,
    _Float16* __restrict__ yl0, _Float16* __restrict__ yl1)
{
    int idx = blockIdx.x * 256 + threadIdx.x;        // grid 392
    if (idx < 32768) { WoB[idx] = (_Float16)Wo[idx]; return; }
    if (idx < 34816) {
        int n = idx - 32768;
        float b = bih[n] + bhh[n];
        b0v[n] = b;
        float a = b;
        #pragma unroll 16
        for (int p = 0; p < 64; ++p) a += Wih[n * 64 + p] * bo[p];
        b1v[n] = a;
        return;
    }
    if (idx < 100352) {
        int e = idx - 34816;
        int m = e >> 6, nn = e & 63;
        float v = x[m * 2048 + 31 * 64 + nn];        // x[:, -1, :]
        yf0[e] = v; yf1[e] = v;
        _Float16 hi = (_Float16)v;
        _Float16 lo = (_Float16)(v - (float)hi);
        yh0[e] = hi; yh1[e] = hi;
        yl0[e] = lo; yl1[e] = lo;
    }
}

extern "C" __global__ void __launch_bounds__(256) k_h0(
    const float* __restrict__ z, const float* __restrict__ Wp, const float* __restrict__ bp,
    float* __restrict__ cst, _Float16* __restrict__ hh0, _Float16* __restrict__ hl0)
{
    int bx = blockIdx.x;                             // grid 2048
    int m = bx >> 1;
    int n = ((bx & 1) << 8) + threadIdx.x;
    float acc = bp[n];
    const f4* zr = (const f4*)&z[m * 128];
    const f4* wr = (const f4*)&Wp[n * 128];
    #pragma unroll 8
    for (int p = 0; p < 32; ++p) {
        f4 zv = zr[p], wv = wr[p];
        acc += zv[0]*wv[0] + zv[1]*wv[1] + zv[2]*wv[2] + zv[3]*wv[3];
    }
    cst[m * 512 + n] = acc;
    _Float16 hi = (_Float16)acc;
    hh0[m * 512 + n] = hi;
    hl0[m * 512 + n] = (_Float16)(acc - (float)hi);
}

// ---- per-mt-group barrier (16 blocks; groups never exchange data with each other) ----
// Release fetch_add orders this block's prior atomic state-stores. Spin MUST be an
// agent-scope load: workgroup-scope spin reads the non-coherent local L2 and can
// miss remote-XCD arrivals forever (R5 deadlock). No blanket acquire fence: state
// reads are themselves agent-coherent atomics, so weights stay L2-resident.
__device__ __forceinline__ void group_bar(unsigned int* cnt, unsigned int target) {
    __syncthreads();
    if (threadIdx.x == 0) {
        __hip_atomic_fetch_add(cnt, 1u, __ATOMIC_RELEASE, __HIP_MEMORY_SCOPE_AGENT);
        while (__hip_atomic_load(cnt, __ATOMIC_RELAXED, __HIP_MEMORY_SCOPE_AGENT) < target)
            __builtin_amdgcn_s_sleep(1);
    }
    __syncthreads();
}

// ---------------- persistent step-loop kernel ----------------
// grid 256: block (mt, s): rows m0..m0+64, h-cols j0..j0+32 (all 4 gate quadrants)
// A layout (K=1152): [y_hi(0..64) | y_lo(64..128) | h_hi(128..640) | h_lo(640..1152)]
extern "C" __global__ void __launch_bounds__(256) k_loop(
    const _Float16* __restrict__ WA, const _Float16* __restrict__ WB,
    const float* __restrict__ b0v, const float* __restrict__ b1v,
    const _Float16* __restrict__ WoB, const float* __restrict__ bout,
    _Float16* __restrict__ hh0, _Float16* __restrict__ hh1,
    _Float16* __restrict__ hl0, _Float16* __restrict__ hl1,
    float* __restrict__ cst,
    float* __restrict__ yf0, float* __restrict__ yf1,
    _Float16* __restrict__ yh0, _Float16* __restrict__ yh1,
    _Float16* __restrict__ yl0, _Float16* __restrict__ yl1,
    float* __restrict__ dl0, float* __restrict__ dl1,
    float* __restrict__ out, unsigned int* __restrict__ bar)
{
    __shared__ __align__(16) unsigned char smem[49152];
    _Float16* sA  = (_Float16*)smem;                             // A chunk: 64 x LDA (37,888 B)
    float*    sEx = (float*)smem;                                // overlay: [4][64][EXS] = 33,792 B
    _Float16* sHh = (_Float16*)(smem + 33792);                   // [64][HSTR] = 7,168 B
    _Float16* sHl = (_Float16*)(smem + 33792 + 7168);            // [64][HSTR]

    const int tid = threadIdx.x;
    const int bx  = blockIdx.x;
    const int mt  = bx >> 4, s = bx & 15;
    const int m0  = mt * 64, j0 = s * 32;
    unsigned int* mybar = bar + mt * 32;             // 128 B per group counter

    const int wv = tid >> 6, lane = tid & 63, l15 = lane & 15, quad = lane >> 4;
    const int quad8 = quad * 8;
    const int brow0 = (wv * 512 + j0 + l15) * 576;
    const int brow1 = (wv * 512 + j0 + 16 + l15) * 576;
    const half8 bw = *(const half8*)&WoB[(wv * 16 + l15) * 512 + j0 + quad8];   // loop-invariant

    const f4 zero = {0.0f, 0.0f, 0.0f, 0.0f};

    #pragma unroll 1
    for (int t = 0; t <= 128; ++t) {
        const int pi = t & 1;
        const _Float16* Wcat  = t ? WB : WA;
        const float*    bias  = t ? b1v : b0v;
        const _Float16* hh_in = pi ? hh1 : hh0;   _Float16* hh_out = pi ? hh0 : hh1;
        const _Float16* hl_in = pi ? hl1 : hl0;   _Float16* hl_out = pi ? hl0 : hl1;
        const float*    yf_in = pi ? yf1 : yf0;   float*    yf_out = pi ? yf0 : yf1;
        const _Float16* yh_in = pi ? yh1 : yh0;   _Float16* yh_out = pi ? yh0 : yh1;
        const _Float16* yl_in = pi ? yl1 : yl0;   _Float16* yl_out = pi ? yl0 : yl1;
        const float*    dl_in = pi ? dl0 : dl1;   float*    dl_out = pi ? dl1 : dl0;

        // ---- resolve y_{t-1} = y_{t-2} + b_out + sum_s Delta_{t-1,s} (4 rows per block) ----
        if (t >= 1 && tid < 64) {
            int row = m0 + s * 4 + (tid >> 4);
            int c4  = (tid & 15) * 4;
            f4 a = ald16f(&yf_in[row * 64 + c4]);
            a += *(const f4*)&bout[c4];
            #pragma unroll
            for (int sp = 0; sp < 16; ++sp)
                a += ald16f(&dl_in[sp * 65536 + row * 64 + c4]);
            ast(&yf_out[row * 64 + c4],     (u64)__float_as_uint(a[0]) | ((u64)__float_as_uint(a[1]) << 32));
            ast(&yf_out[row * 64 + c4 + 2], (u64)__float_as_uint(a[2]) | ((u64)__float_as_uint(a[3]) << 32));
            *(f4*)&out[row * 8192 + (t - 1) * 64 + c4] = a;
            unsigned short hi4[4], lo4[4];
            #pragma unroll
            for (int x = 0; x < 4; ++x) {
                _Float16 h16 = (_Float16)a[x];
                _Float16 l16 = (_Float16)(a[x] - (float)h16);
                hi4[x] = __builtin_bit_cast(unsigned short, h16);
                lo4[x] = __builtin_bit_cast(unsigned short, l16);
            }
            ast(&yh_out[row * 64 + c4],
                (u64)hi4[0] | ((u64)hi4[1] << 16) | ((u64)hi4[2] << 32) | ((u64)hi4[3] << 48));
            ast(&yl_out[row * 64 + c4],
                (u64)lo4[0] | ((u64)lo4[1] << 16) | ((u64)lo4[2] << 32) | ((u64)lo4[3] << 48));
        }
        if (t >= 128) break;

        f4 acc[4][2];
        #pragma unroll
        for (int a = 0; a < 4; ++a) { acc[a][0] = zero; acc[a][1] = zero; }

        // ---- 4 staged chunks of K=288 over the split-A (K=1152) gates GEMM ----
        #pragma unroll
        for (int ch = 0; ch < 4; ++ch) {
            if (ch) __syncthreads();                 // previous chunk's MFMAs done
            #pragma unroll
            for (int it = 0; it < 18; ++it) {        // 18*256*8B = 64 rows x 288 halves
                int i8 = it * 256 + tid;
                int r = i8 / 72, c8 = i8 % 72;       // u64 index within row
                int g = ch * 288 + c8 * 4;
                const void* src;
                if (g < 64)       src = yh_in + (m0 + r) * 64 + g;
                else if (g < 128) src = yl_in + (m0 + r) * 64 + (g - 64);
                else if (g < 640) src = hh_in + (m0 + r) * 512 + (g - 128);
                else              src = hl_in + (m0 + r) * 512 + (g - 640);
                *(u64*)&sA[r * LDA + c8 * 4] = ald(src);
            }
            __syncthreads();
            #pragma unroll
            for (int kc = 0; kc < 9; ++kc) {
                const int g0  = ch * 288 + kc * 32;
                const int bc0 = (g0 < 64) ? g0 : ((g0 < 640) ? g0 - 64 : g0 - 576);
                int kq = kc * 32 + quad8;
                int bq = bc0 + quad8;
                half8 a0 = *(const half8*)&sA[(l15     ) * LDA + kq];
                half8 a1 = *(const half8*)&sA[(l15 + 16) * LDA + kq];
                half8 a2 = *(const half8*)&sA[(l15 + 32) * LDA + kq];
                half8 a3 = *(const half8*)&sA[(l15 + 48) * LDA + kq];
                half8 b0 = *(const half8*)&Wcat[brow0 + bq];
                half8 b1 = *(const half8*)&Wcat[brow1 + bq];
                acc[0][0] = __builtin_amdgcn_mfma_f32_16x16x32_f16(a0, b0, acc[0][0], 0, 0, 0);
                acc[1][0] = __builtin_amdgcn_mfma_f32_16x16x32_f16(a1, b0, acc[1][0], 0, 0, 0);
                acc[2][0] = __builtin_amdgcn_mfma_f32_16x16x32_f16(a2, b0, acc[2][0], 0, 0, 0);
                acc[3][0] = __builtin_amdgcn_mfma_f32_16x16x32_f16(a3, b0, acc[3][0], 0, 0, 0);
                acc[0][1] = __builtin_amdgcn_mfma_f32_16x16x32_f16(a0, b1, acc[0][1], 0, 0, 0);
                acc[1][1] = __builtin_amdgcn_mfma_f32_16x16x32_f16(a1, b1, acc[1][1], 0, 0, 0);
                acc[2][1] = __builtin_amdgcn_mfma_f32_16x16x32_f16(a2, b1, acc[2][1], 0, 0, 0);
                acc[3][1] = __builtin_amdgcn_mfma_f32_16x16x32_f16(a3, b1, acc[3][1], 0, 0, 0);
            }
        }
        __syncthreads();                              // sA dead -> overlay exchange

        // ---- gate exchange: wave wv = quadrant wv (i,f,g,o). D: col=lane&15, row=quad*4+reg ----
        #pragma unroll
        for (int a = 0; a < 4; ++a)
            #pragma unroll
            for (int b = 0; b < 2; ++b)
                #pragma unroll
                for (int r = 0; r < 4; ++r)
                    sEx[(wv * 64 + a * 16 + quad * 4 + r) * EXS + b * 16 + l15] = acc[a][b][r];
        __syncthreads();

        // ---- LSTM cell update: thread -> row m, 8 h-cols ----
        {
            int m = tid >> 2, jb = (tid & 3) * 8;
            int jcol = j0 + jb;
            int crow = (m0 + m) * 512 + jcol;
            f4 c0 = *(const f4*)&cst[crow];
            f4 c1 = *(const f4*)&cst[crow + 4];
            unsigned short hi8[8], lo8[8];
            #pragma unroll
            for (int x = 0; x < 8; ++x) {
                float gi = sEx[(0 * 64 + m) * EXS + jb + x] + bias[       jcol + x];
                float gf = sEx[(1 * 64 + m) * EXS + jb + x] + bias[ 512 + jcol + x];
                float gg = sEx[(2 * 64 + m) * EXS + jb + x] + bias[1024 + jcol + x];
                float go = sEx[(3 * 64 + m) * EXS + jb + x] + bias[1536 + jcol + x];
                float iv = sigm(gi), fv = sigm(gf), gv = tanh_(gg), ov = sigm(go);
                float cold = (x < 4) ? c0[x] : c1[x - 4];
                float cn = fv * cold + iv * gv;
                float hn = ov * tanh_(cn);
                if (x < 4) c0[x] = cn; else c1[x - 4] = cn;
                _Float16 h16 = (_Float16)hn;
                _Float16 l16 = (_Float16)(hn - (float)h16);
                hi8[x] = __builtin_bit_cast(unsigned short, h16);
                lo8[x] = __builtin_bit_cast(unsigned short, l16);
            }
            *(f4*)&cst[crow]     = c0;               // block-local, plain
            *(f4*)&cst[crow + 4] = c1;
            u64 ph0 = (u64)hi8[0] | ((u64)hi8[1] << 16) | ((u64)hi8[2] << 32) | ((u64)hi8[3] << 48);
            u64 ph1 = (u64)hi8[4] | ((u64)hi8[5] << 16) | ((u64)hi8[6] << 32) | ((u64)hi8[7] << 48);
            u64 pl0 = (u64)lo8[0] | ((u64)lo8[1] << 16) | ((u64)lo8[2] << 32) | ((u64)lo8[3] << 48);
            u64 pl1 = (u64)lo8[4] | ((u64)lo8[5] << 16) | ((u64)lo8[6] << 32) | ((u64)lo8[7] << 48);
            ast(&hh_out[crow],     ph0); ast(&hh_out[crow + 4], ph1);
            ast(&hl_out[crow],     pl0); ast(&hl_out[crow + 4], pl1);
            *(u64*)&sHh[m * HSTR + jb]     = ph0;    // LDS copy for Delta GEMM
            *(u64*)&sHh[m * HSTR + jb + 4] = ph1;
            *(u64*)&sHl[m * HSTR + jb]     = pl0;
            *(u64*)&sHl[m * HSTR + jb + 4] = pl1;
        }
        __syncthreads();

        // ---- Delta partial: dl_out[s] = (h_hi+h_lo)(strip) @ Wout^T, K=32 per m-tile ----
        {
            f4 d[4];
            #pragma unroll
            for (int a = 0; a < 4; ++a) d[a] = zero;
            #pragma unroll
            for (int a = 0; a < 4; ++a) {
                half8 ahh = *(const half8*)&sHh[(a * 16 + l15) * HSTR + quad8];
                half8 ahl = *(const half8*)&sHl[(a * 16 + l15) * HSTR + quad8];
                d[a] = __builtin_amdgcn_mfma_f32_16x16x32_f16(ahh, bw, d[a], 0, 0, 0);
                d[a] = __builtin_amdgcn_mfma_f32_16x16x32_f16(ahl, bw, d[a], 0, 0, 0);
            }
            #pragma unroll
            for (int a = 0; a < 4; ++a) {
                float* dst = &dl_out[s * 65536 + (m0 + a * 16 + quad * 4) * 64 + wv * 16 + l15];
                #pragma unroll
                for (int r = 0; r < 4; ++r)
                    __hip_atomic_store(&dst[r * 64], d[a][r], __ATOMIC_RELAXED, __HIP_MEMORY_SCOPE_AGENT);
            }
        }

        group_bar(mybar, 16u * (unsigned)(t + 1));
    }
}

// ---------------- host ----------------
extern "C" void kernel_launch(void* const* d_in, const int* in_sizes, int n_in,
                              void* d_out, int out_size, void* d_ws, size_t ws_size,
                              hipStream_t stream)
{
    const float* z   = (const float*)d_in[0];
    const float* x   = (const float*)d_in[1];
    const float* Wih = (const float*)d_in[2];
    const float* Whh = (const float*)d_in[3];
    const float* bih = (const float*)d_in[4];
    const float* bhh = (const float*)d_in[5];
    const float* Wp  = (const float*)d_in[6];
    const float* bp  = (const float*)d_in[7];
    const float* Wo  = (const float*)d_in[8];
    const float* bo  = (const float*)d_in[9];

    char* w = (char*)d_ws;
    _Float16* WA  = (_Float16*)w; w += 2359296;   // [2048][576] fp16
    _Float16* WB  = (_Float16*)w; w += 2359296;
    _Float16* WoB = (_Float16*)w; w += 65536;     // [64][512] fp16
    float* b0v = (float*)w; w += 8192;
    float* b1v = (float*)w; w += 8192;
    _Float16* hh[2];
    hh[0] = (_Float16*)w; w += 1048576;
    hh[1] = (_Float16*)w; w += 1048576;
    _Float16* hl[2];
    hl[0] = (_Float16*)w; w += 1048576;
    hl[1] = (_Float16*)w; w += 1048576;
    float* cst = (float*)w; w += 2097152;
    float* yf[2];
    yf[0] = (float*)w; w += 262144;
    yf[1] = (float*)w; w += 262144;
    _Float16* yh[2];
    yh[0] = (_Float16*)w; w += 131072;
    yh[1] = (_Float16*)w; w += 131072;
    _Float16* yl[2];
    yl[0] = (_Float16*)w; w += 131072;
    yl[1] = (_Float16*)w; w += 131072;
    float* dl[2];
    dl[0] = (float*)w; w += 4194304;              // [16][1024][64] fp32
    dl[1] = (float*)w; w += 4194304;
    unsigned int* bar = (unsigned int*)w; w += 2048;   // 16 group counters, 128B apart
    float* out = (float*)d_out;

    (void)hipMemsetAsync(bar, 0, 2048, stream);
    k_wcat<<<4608, 256, 0, stream>>>(Wih, Whh, WA, WB);
    k_comb<<<4096, 256, 0, stream>>>(Wih, Whh, Wo, WB);
    k_misc<<<392, 256, 0, stream>>>(Wo, bih, bhh, Wih, bo, x, WoB, b0v, b1v,
                                    yf[0], yf[1], yh[0], yh[1], yl[0], yl[1]);
    k_h0<<<2048, 256, 0, stream>>>(z, Wp, bp, cst, hh[0], hl[0]);

    k_loop<<<256, 256, 0, stream>>>(
        WA, WB, b0v, b1v, WoB, bo,
        hh[0], hh[1], hl[0], hl[1], cst,
        yf[0], yf[1], yh[0], yh[1], yl[0], yl[1],
        dl[0], dl[1], out, bar);
}

// Round 8
// 3604.626 us; speedup vs baseline: 1.9144x; 1.5199x over previous
//
#include <hip/hip_runtime.h>
#include <stdint.h>

typedef _Float16 half8 __attribute__((ext_vector_type(8)));  // 8 fp16 (4 VGPR) MFMA frag
typedef __attribute__((ext_vector_type(4))) float f4;        // fp32x4 accum
typedef unsigned long long u64;

// LDS geometry (16 rows/block)
#define HS   1056   // sH row stride (halves): [hi 0..512 | lo 512..1024 | pad]; 16*HS*2 = 33792 B
#define EXR  132    // sEx row stride (floats); wave region 16*EXR = 2112 floats
#define SYR  136    // sY row stride (halves): [hi 0..64 | lo 64..128 | pad]
#define YDR  68     // sYd / yR row stride (floats)
#define CRR  132    // cR row stride (floats)

__device__ __forceinline__ float sigm(float x) { return 1.0f / (1.0f + __expf(-x)); }
__device__ __forceinline__ float tanh_(float x) { return 1.0f - 2.0f / (__expf(2.0f * x) + 1.0f); }

// agent-scope relaxed 8B atomics: per-access coherent cross-XCD state exchange
__device__ __forceinline__ u64 ald(const void* p) {
    return __hip_atomic_load((const u64*)p, __ATOMIC_RELAXED, __HIP_MEMORY_SCOPE_AGENT);
}
__device__ __forceinline__ void ast(void* p, u64 v) {
    __hip_atomic_store((u64*)p, v, __ATOMIC_RELAXED, __HIP_MEMORY_SCOPE_AGENT);
}

// ---------------- prologue kernels ----------------

// Wcat[2048][576] = [W_ih | W_hh] fp16
extern "C" __global__ void __launch_bounds__(256) k_wcat(
    const float* __restrict__ Wih, const float* __restrict__ Whh,
    _Float16* __restrict__ WA)
{
    int idx = blockIdx.x * 256 + threadIdx.x;        // grid 4608 = 2048*576/256
    int n = idx / 576, k = idx % 576;
    float v = (k < 64) ? Wih[n * 64 + k] : Whh[n * 512 + (k - 64)];
    WA[idx] = (_Float16)v;
}

// WoB fp16 [64][512]; b0v = b_ih + b_hh
extern "C" __global__ void __launch_bounds__(256) k_misc(
    const float* __restrict__ Wo, const float* __restrict__ bih, const float* __restrict__ bhh,
    _Float16* __restrict__ WoB, float* __restrict__ b0v)
{
    int idx = blockIdx.x * 256 + threadIdx.x;        // grid 136
    if (idx < 32768) { WoB[idx] = (_Float16)Wo[idx]; return; }
    if (idx < 34816) {
        int n = idx - 32768;
        b0v[n] = bih[n] + bhh[n];
    }
}

// h0 = z @ Wproj^T + b_proj ; c0 = h0 (fp32) ; h0 stored fp16 hi/lo
extern "C" __global__ void __launch_bounds__(256) k_h0(
    const float* __restrict__ z, const float* __restrict__ Wp, const float* __restrict__ bp,
    float* __restrict__ cst, _Float16* __restrict__ hh0, _Float16* __restrict__ hl0)
{
    int bx = blockIdx.x;                             // grid 2048
    int m = bx >> 1;
    int n = ((bx & 1) << 8) + threadIdx.x;
    float acc = bp[n];
    const f4* zr = (const f4*)&z[m * 128];
    const f4* wr = (const f4*)&Wp[n * 128];
    #pragma unroll 8
    for (int p = 0; p < 32; ++p) {
        f4 zv = zr[p], wv = wr[p];
        acc += zv[0]*wv[0] + zv[1]*wv[1] + zv[2]*wv[2] + zv[3]*wv[3];
    }
    cst[m * 512 + n] = acc;
    _Float16 hi = (_Float16)acc;
    hh0[m * 512 + n] = hi;
    hl0[m * 512 + n] = (_Float16)(acc - (float)hi);
}

// ---- per-group barrier (4 blocks share h rows; agent-scope spin — R6-proven) ----
__device__ __forceinline__ void group_bar(unsigned int* cnt, unsigned int target) {
    __syncthreads();
    if (threadIdx.x == 0) {
        __hip_atomic_fetch_add(cnt, 1u, __ATOMIC_RELEASE, __HIP_MEMORY_SCOPE_AGENT);
        while (__hip_atomic_load(cnt, __ATOMIC_RELAXED, __HIP_MEMORY_SCOPE_AGENT) < target)
            __builtin_amdgcn_s_sleep(1);
    }
    __syncthreads();
}

// ---------------- persistent step-loop kernel ----------------
// grid 256 = 64 groups (g) x 4 strips (s). Block: rows m0=g*16..+16, h-cols j0=s*128..+128,
// gate-cols q*512 + j0..+128 for q=0..3 (wave q computes gate q).
// sH [16][HS]: h_t hi|lo (K=1024).  sY [16][SYR]: y_{t-1} hi|lo (never overlaid).
// sEx overlays sH exactly (33792 B).  y and c are block-local; only h crosses blocks.
extern "C" __global__ void __launch_bounds__(256) k_loop(
    const _Float16* __restrict__ Wcat, const float* __restrict__ b0v,
    const _Float16* __restrict__ WoB, const float* __restrict__ bout,
    const float* __restrict__ x, const float* __restrict__ cst,
    _Float16* __restrict__ hh0, _Float16* __restrict__ hh1,
    _Float16* __restrict__ hl0, _Float16* __restrict__ hl1,
    float* __restrict__ out, unsigned int* __restrict__ bar)
{
    __shared__ __align__(16) unsigned char smem[55296];
    _Float16* sH  = (_Float16*)smem;                  // [16][HS] = 33792 B
    float*    sEx = (float*)smem;                     // overlay: [4][16][EXR] = 33792 B
    _Float16* sY  = (_Float16*)(smem + 33792);        // [16][SYR] = 4352 B
    float*    sYd = (float*)(smem + 38144);           // [16][YDR] = 4352 B
    float*    cR  = (float*)(smem + 42496);           // [16][CRR] = 8448 B
    float*    yR  = (float*)(smem + 50944);           // [16][YDR] = 4352 B

    const int tid = threadIdx.x;
    const int bx  = blockIdx.x;
    const int g   = bx >> 2, s = bx & 3;
    const int m0  = g * 16, j0 = s * 128;
    unsigned int* mybar = bar + g * 32;               // 128 B apart

    const int wv = tid >> 6, lane = tid & 63, l15 = lane & 15, quad = lane >> 4;
    const int quad8 = quad * 8;

    // B row bases for the gates GEMM (8 n-tiles of 16 gate-cols per wave = 128 cols)
    int brow[8];
    #pragma unroll
    for (int n = 0; n < 8; ++n)
        brow[n] = (wv * 512 + j0 + n * 16 + l15) * 576;
    const int yrow = (wv * 16 + l15) * 512;           // WoB row base for y-GEMM

    const f4 zero = {0.0f, 0.0f, 0.0f, 0.0f};

    // ---- init: y_{-1} = x[:,-1,:] -> yR (fp32) + sY (hi/lo); c = c0 -> cR ----
    #pragma unroll
    for (int it = 0; it < 4; ++it) {
        int i = it * 256 + tid;                       // 1024 = 16 x 64
        int r = i >> 6, yc = i & 63;
        float v = x[(m0 + r) * 2048 + 1984 + yc];
        yR[r * YDR + yc] = v;
        _Float16 hi = (_Float16)v;
        sY[r * SYR + yc]      = hi;
        sY[r * SYR + 64 + yc] = (_Float16)(v - (float)hi);
    }
    #pragma unroll
    for (int it = 0; it < 8; ++it) {
        int i = it * 256 + tid;                       // 2048 = 16 x 128
        int r = i >> 7, cc = i & 127;
        cR[r * CRR + cc] = cst[(m0 + r) * 512 + j0 + cc];
    }

    #pragma unroll 1
    for (int t = 0; t <= 128; ++t) {
        const int pi = t & 1;
        const _Float16* hh_in = pi ? hh1 : hh0;   _Float16* hh_out = pi ? hh0 : hh1;
        const _Float16* hl_in = pi ? hl1 : hl0;   _Float16* hl_out = pi ? hl0 : hl1;

        // ---- stage h_t rows m0..m0+16 (hi+lo) into sH: 4096 u64, 16/thread, batched ----
        {
            u64 tmp[16];
            #pragma unroll
            for (int j = 0; j < 8; ++j) {
                int i = j * 256 + tid;                // 2048 u64 per half
                int r = i >> 7, c = (i & 127) * 4;
                tmp[j]     = ald(hh_in + (m0 + r) * 512 + c);
                tmp[j + 8] = ald(hl_in + (m0 + r) * 512 + c);
            }
            #pragma unroll
            for (int j = 0; j < 8; ++j) {
                int i = j * 256 + tid;
                int r = i >> 7, c = (i & 127) * 4;
                *(u64*)&sH[r * HS + c]       = tmp[j];
                *(u64*)&sH[r * HS + 512 + c] = tmp[j + 8];
            }
        }
        __syncthreads();

        // ---- y-phase: y_{t-1} = y_{t-2} + h_t @ Wout^T + b_out ----
        if (t >= 1) {
            f4 accy = zero;
            #pragma unroll
            for (int kf = 0; kf < 16; ++kf) {
                half8 bf  = *(const half8*)&WoB[yrow + kf * 32 + quad8];
                half8 ahi = *(const half8*)&sH[l15 * HS + kf * 32 + quad8];
                half8 alo = *(const half8*)&sH[l15 * HS + 512 + kf * 32 + quad8];
                accy = __builtin_amdgcn_mfma_f32_16x16x32_f16(ahi, bf, accy, 0, 0, 0);
                accy = __builtin_amdgcn_mfma_f32_16x16x32_f16(alo, bf, accy, 0, 0, 0);
            }
            // D layout: col = lane&15 (y-col within wave's 16), row = quad*4 + reg
            #pragma unroll
            for (int r4 = 0; r4 < 4; ++r4)
                sYd[(quad * 4 + r4) * YDR + wv * 16 + l15] = accy[r4];
            __syncthreads();
            // clean (row, col) scalar update: thread -> row r, 4 y-cols
            {
                int r = tid >> 4, c0 = (tid & 15) * 4;
                f4 a = *(const f4*)&yR[r * YDR + c0];
                a += *(const f4*)&sYd[r * YDR + c0];
                a += *(const f4*)&bout[c0];
                *(f4*)&yR[r * YDR + c0] = a;
                if (s == 0)
                    *(f4*)&out[(m0 + r) * 8192 + (t - 1) * 64 + c0] = a;
                unsigned short h4[4], l4[4];
                #pragma unroll
                for (int xx = 0; xx < 4; ++xx) {
                    _Float16 hi = (_Float16)a[xx];
                    _Float16 lo = (_Float16)(a[xx] - (float)hi);
                    h4[xx] = __builtin_bit_cast(unsigned short, hi);
                    l4[xx] = __builtin_bit_cast(unsigned short, lo);
                }
                *(u64*)&sY[r * SYR + c0] =
                    (u64)h4[0] | ((u64)h4[1] << 16) | ((u64)h4[2] << 32) | ((u64)h4[3] << 48);
                *(u64*)&sY[r * SYR + 64 + c0] =
                    (u64)l4[0] | ((u64)l4[1] << 16) | ((u64)l4[2] << 32) | ((u64)l4[3] << 48);
            }
        }
        if (t >= 128) break;
        __syncthreads();                              // sY/y-phase visible to gates

        // ---- gates GEMM: 16 rows x 512 gate-cols (wave=gate), K=(64+512) x hi/lo ----
        f4 acc[8];
        #pragma unroll
        for (int n = 0; n < 8; ++n) acc[n] = zero;

        #pragma unroll
        for (int kk = 0; kk < 18; ++kk) {
            half8 ahi, alo;
            int bc;
            if (kk < 2) {                             // y frames (K 0..64 of Wcat)
                ahi = *(const half8*)&sY[l15 * SYR + kk * 32 + quad8];
                alo = *(const half8*)&sY[l15 * SYR + 64 + kk * 32 + quad8];
                bc  = kk * 32;
            } else {                                  // h frames (K 64..576 of Wcat)
                ahi = *(const half8*)&sH[l15 * HS + (kk - 2) * 32 + quad8];
                alo = *(const half8*)&sH[l15 * HS + 512 + (kk - 2) * 32 + quad8];
                bc  = 64 + (kk - 2) * 32;
            }
            #pragma unroll
            for (int n = 0; n < 8; ++n) {
                half8 bf = *(const half8*)&Wcat[brow[n] + bc + quad8];
                acc[n] = __builtin_amdgcn_mfma_f32_16x16x32_f16(ahi, bf, acc[n], 0, 0, 0);
                acc[n] = __builtin_amdgcn_mfma_f32_16x16x32_f16(alo, bf, acc[n], 0, 0, 0);
            }
        }
        __syncthreads();                              // sH dead -> sEx overlay

        // ---- gate exchange: wave wv = gate wv. D: col=lane&15, row=quad*4+reg ----
        #pragma unroll
        for (int n = 0; n < 8; ++n)
            #pragma unroll
            for (int r4 = 0; r4 < 4; ++r4)
                sEx[wv * (16 * EXR) + (quad * 4 + r4) * EXR + n * 16 + l15] = acc[n][r4];
        __syncthreads();

        // ---- LSTM cell update: thread -> row r, 8 strip-cols ----
        {
            int r = tid >> 4, cc = (tid & 15) * 8;
            int gb = j0 + cc;
            f4 c0 = *(const f4*)&cR[r * CRR + cc];
            f4 c1 = *(const f4*)&cR[r * CRR + cc + 4];
            unsigned short hi8[8], lo8[8];
            #pragma unroll
            for (int xx = 0; xx < 8; ++xx) {
                float gi = sEx[0 * (16 * EXR) + r * EXR + cc + xx] + b0v[       gb + xx];
                float gf = sEx[1 * (16 * EXR) + r * EXR + cc + xx] + b0v[ 512 + gb + xx];
                float gg = sEx[2 * (16 * EXR) + r * EXR + cc + xx] + b0v[1024 + gb + xx];
                float go = sEx[3 * (16 * EXR) + r * EXR + cc + xx] + b0v[1536 + gb + xx];
                float iv = sigm(gi), fv = sigm(gf), gv = tanh_(gg), ov = sigm(go);
                float cold = (xx < 4) ? c0[xx] : c1[xx - 4];
                float cn = fv * cold + iv * gv;
                float hn = ov * tanh_(cn);
                if (xx < 4) c0[xx] = cn; else c1[xx - 4] = cn;
                _Float16 h16 = (_Float16)hn;
                _Float16 l16 = (_Float16)(hn - (float)h16);
                hi8[xx] = __builtin_bit_cast(unsigned short, h16);
                lo8[xx] = __builtin_bit_cast(unsigned short, l16);
            }
            *(f4*)&cR[r * CRR + cc]     = c0;
            *(f4*)&cR[r * CRR + cc + 4] = c1;
            u64 ph0 = (u64)hi8[0] | ((u64)hi8[1] << 16) | ((u64)hi8[2] << 32) | ((u64)hi8[3] << 48);
            u64 ph1 = (u64)hi8[4] | ((u64)hi8[5] << 16) | ((u64)hi8[6] << 32) | ((u64)hi8[7] << 48);
            u64 pl0 = (u64)lo8[0] | ((u64)lo8[1] << 16) | ((u64)lo8[2] << 32) | ((u64)lo8[3] << 48);
            u64 pl1 = (u64)lo8[4] | ((u64)lo8[5] << 16) | ((u64)lo8[6] << 32) | ((u64)lo8[7] << 48);
            int hrow = (m0 + r) * 512 + j0 + cc;
            ast(hh_out + hrow,     ph0); ast(hh_out + hrow + 4, ph1);
            ast(hl_out + hrow,     pl0); ast(hl_out + hrow + 4, pl1);
        }

        group_bar(mybar, 4u * (unsigned)(t + 1));
    }
}

// ---------------- host ----------------
extern "C" void kernel_launch(void* const* d_in, const int* in_sizes, int n_in,
                              void* d_out, int out_size, void* d_ws, size_t ws_size,
                              hipStream_t stream)
{
    const float* z   = (const float*)d_in[0];
    const float* x   = (const float*)d_in[1];
    const float* Wih = (const float*)d_in[2];
    const float* Whh = (const float*)d_in[3];
    const float* bih = (const float*)d_in[4];
    const float* bhh = (const float*)d_in[5];
    const float* Wp  = (const float*)d_in[6];
    const float* bp  = (const float*)d_in[7];
    const float* Wo  = (const float*)d_in[8];
    const float* bo  = (const float*)d_in[9];

    char* w = (char*)d_ws;
    _Float16* WA  = (_Float16*)w; w += 2359296;   // [2048][576] fp16
    _Float16* WoB = (_Float16*)w; w += 65536;     // [64][512] fp16
    float* b0v = (float*)w; w += 8192;
    _Float16* hh[2];
    hh[0] = (_Float16*)w; w += 1048576;
    hh[1] = (_Float16*)w; w += 1048576;
    _Float16* hl[2];
    hl[0] = (_Float16*)w; w += 1048576;
    hl[1] = (_Float16*)w; w += 1048576;
    float* cst = (float*)w; w += 2097152;
    unsigned int* bar = (unsigned int*)w; w += 8192;   // 64 group counters, 128 B apart
    float* out = (float*)d_out;

    (void)hipMemsetAsync(bar, 0, 8192, stream);
    k_wcat<<<4608, 256, 0, stream>>>(Wih, Whh, WA);
    k_misc<<<136, 256, 0, stream>>>(Wo, bih, bhh, WoB, b0v);
    k_h0<<<2048, 256, 0, stream>>>(z, Wp, bp, cst, hh[0], hl[0]);

    k_loop<<<256, 256, 0, stream>>>(
        WA, b0v, WoB, bo, x, cst,
        hh[0], hh[1], hl[0], hl[1],
        out, bar);
}